// Round 15
// baseline (610.115 us; speedup 1.0000x reference)
//
#include <hip/hip_runtime.h>
#include <math.h>

typedef unsigned short u16;
typedef unsigned int u32;
using bf16x8 = __attribute__((ext_vector_type(8))) short;
using f32x4  = __attribute__((ext_vector_type(4))) float;

#define DD 4096
#define NB 256            // batch
#define SPLIT_K 4
#define PSTRIDE (NB * DD) // elements per partial plane
#define PLANE (NB * DD)   // floats per transform layer plane

__device__ __forceinline__ u16 f2bf(float f) {
  unsigned int u = __float_as_uint(f);
  u += 0x7fffu + ((u >> 16) & 1u);   // RNE
  return (u16)(u >> 16);
}
__device__ __forceinline__ float bf2f(u16 h) {
  return __uint_as_float((u32)h << 16);
}
__device__ __forceinline__ unsigned int pack2bf(float a, float b) {
  return (unsigned int)f2bf(a) | ((unsigned int)f2bf(b) << 16);
}
__device__ __forceinline__ void async_cp16(const u16* g, u16* l) {
  __builtin_amdgcn_global_load_lds(
      (const __attribute__((address_space(1))) unsigned int*)g,
      (__attribute__((address_space(3))) unsigned int*)l, 16, 0, 0);
}

// ---------------------------------------------------------------------------
// GEMM (R11 body, unchanged): part[kz] = Xf(bf16) @ W^T, output bf16.
// Tile 128x64 (M-split 2), K-chunk 1024 (16 iters of BK=64).
// ---------------------------------------------------------------------------
__global__ __launch_bounds__(512, 8) void gemm_kernel(
    const u16* __restrict__ A, const float* __restrict__ W,
    u16* __restrict__ part)
{
  const int nt = blockIdx.x;
  const int mt = blockIdx.y & 1;
  const int kz = blockIdx.y >> 1;
  const int t = threadIdx.x;
  const int w = t >> 6, l = t & 63;

  __shared__ __align__(16) u16 As[128 * 64];   // 16 KB
  __shared__ __align__(16) u16 Bs[64 * 64];    // 8 KB

  const int colg0 = nt << 6;
  const int m0 = mt << 7;
  const int k0 = kz << 10;                     // K-chunk of 1024

  f32x4 acc[2][2];
#pragma unroll
  for (int mi = 0; mi < 2; ++mi)
#pragma unroll
    for (int nj = 0; nj < 2; ++nj)
      acc[mi][nj] = (f32x4){0.f, 0.f, 0.f, 0.f};

  const int wm = w & 3, wn = w >> 2;      // wave tile: rows 32*wm, cols 32*wn
  const int lr = l & 15, lg = l >> 4;
  const int arow_l = (w << 3) + (l >> 3); // A stage row (+64 for 2nd load)
  const int acl = l & 7;                  // linear chunk within row
  const int bn_l = t >> 3;                // B stage: W row (output col)
  const int bcc = t & 7;                  // B stage: chunk

  for (int tt = 0; tt < 16; ++tt) {
    const int kk = k0 + (tt << 6);
    __syncthreads();                      // LDS safe to overwrite
#pragma unroll
    for (int r2 = 0; r2 < 2; ++r2) {
      const int row = (r2 << 6) + arow_l;
      const int cs = acl ^ (row & 7);
      async_cp16(A + ((size_t)(m0 + row) << 12) + kk + (cs << 3),
                 &As[(r2 << 12) + (w << 9)]);
    }
    {
      const float* wsrc = W + ((size_t)(colg0 + bn_l) << 12) + kk + (bcc << 3);
      const float4 f0 = *reinterpret_cast<const float4*>(wsrc);
      const float4 f1 = *reinterpret_cast<const float4*>(wsrc + 4);
      uint4 pk;
      pk.x = pack2bf(f0.x, f0.y);
      pk.y = pack2bf(f0.z, f0.w);
      pk.z = pack2bf(f1.x, f1.y);
      pk.w = pack2bf(f1.z, f1.w);
      *reinterpret_cast<uint4*>(&Bs[(bn_l << 6) + ((bcc ^ (bn_l & 7)) << 3)]) = pk;
    }
    __syncthreads();                      // vmcnt(0)+lgkmcnt(0)+barrier
#pragma unroll
    for (int ks = 0; ks < 2; ++ks) {
      const int cg = (ks << 2) + lg;
      bf16x8 av[2], bv[2];
#pragma unroll
      for (int mi = 0; mi < 2; ++mi) {
        const int fr = (wm << 5) + (mi << 4) + lr;
        av[mi] = *reinterpret_cast<const bf16x8*>(&As[(fr << 6) + ((cg ^ (fr & 7)) << 3)]);
      }
#pragma unroll
      for (int nj = 0; nj < 2; ++nj) {
        const int fc = (wn << 5) + (nj << 4) + lr;
        bv[nj] = *reinterpret_cast<const bf16x8*>(&Bs[(fc << 6) + ((cg ^ (fc & 7)) << 3)]);
      }
#pragma unroll
      for (int mi = 0; mi < 2; ++mi)
#pragma unroll
        for (int nj = 0; nj < 2; ++nj)
          acc[mi][nj] = __builtin_amdgcn_mfma_f32_16x16x32_bf16(
              av[mi], bv[nj], acc[mi][nj], 0, 0, 0);
    }
  }

  u16* pout = part + (size_t)kz * PSTRIDE;
#pragma unroll
  for (int mi = 0; mi < 2; ++mi)
#pragma unroll
    for (int nj = 0; nj < 2; ++nj) {
      const int col = colg0 + (wn << 5) + (nj << 4) + lr;
#pragma unroll
      for (int j = 0; j < 4; ++j) {
        const int row = m0 + (wm << 5) + (mi << 4) + (lg << 2) + j;
        pout[((size_t)row << 12) + col] = f2bf(acc[mi][nj][j]);
      }
    }
}

// ---------------------------------------------------------------------------
// Per-sample fused update (R11 body, unchanged).
// ---------------------------------------------------------------------------
struct UpdSmem {
  float U[64][17], V[64][17], P[64][17], Q[64][17];
  float S[16][16];
  float sinv[16];
  union {
    struct {
      float dY[64][68];
      float dYT[64][69];
    };
    struct {
      float F[64][17];
      float T1[16][17], G1[16][17], G2[16][17], M1[16][17], dSs[16][17];
      float RS[512];
    };
  };
};

__device__ __forceinline__ void stiefel_update512(
    UpdSmem& m, float (&Am)[64][17], float (&Dm)[64][17],
    int t, float* __restrict__ gout, size_t ub)
{
  const int p = t >> 3;
  const int j0 = (t << 1) & 15;
  {
    const int half = t & 1, i = t >> 5, j = (t >> 1) & 15;
    float a = 0.f;
    const int r0 = half << 5;
    for (int r = r0; r < r0 + 32; ++r) a += Am[r][i] * Dm[r][j];
    m.RS[t] = a;
  }
  __syncthreads();
  if (t < 256) m.T1[t >> 4][t & 15] = m.RS[t << 1] + m.RS[(t << 1) + 1];
  __syncthreads();
  {
    float f0 = Dm[p][j0], f1 = Dm[p][j0 + 1];
    for (int k = 0; k < 16; ++k) {
      const float ak = Am[p][k];
      f0 -= ak * m.T1[k][j0];
      f1 -= ak * m.T1[k][j0 + 1];
    }
    m.F[p][j0] = f0; m.F[p][j0 + 1] = f1;
  }
  __syncthreads();
  if (t < 256) {
    const int i = t >> 4, j = t & 15;
    float g = 0.f;
    for (int r = 0; r < 64; ++r) g += Am[r][i] * m.F[r][j];
    m.G1[i][j] = g;
  } else {
    const int tt = t - 256, i = tt >> 4, j = tt & 15;
    float g = 0.f;
    for (int r = 0; r < 64; ++r) g += Am[r][i] * Am[r][j];
    m.G2[i][j] = g;
  }
  __syncthreads();
  if (t < 256) {
    const int i = t >> 4, j = t & 15;
    float mm = 0.f;
    for (int k = 0; k < 16; ++k) mm += m.G1[i][k] * m.G2[k][j];
    m.M1[i][j] = mm;
  }
  __syncthreads();
  {
    float a0 = 0.f, a1 = 0.f;
    for (int k = 0; k < 16; ++k) {
      const float fk = m.F[p][k];
      a0 += fk * m.M1[k][j0];
      a1 += fk * m.M1[k][j0 + 1];
    }
    const float n0 = Am[p][j0] - 1e-6f * a0;
    const float n1 = Am[p][j0 + 1] - 1e-6f * a1;
    __syncthreads();
    Am[p][j0] = n0; Am[p][j0 + 1] = n1;
    *reinterpret_cast<float2*>(gout + ub + (p << 4) + j0) = make_float2(n0, n1);
  }
  __syncthreads();
}

__device__ __forceinline__ void write_xf_tail(
    UpdSmem& m, int t, int b, float* __restrict__ Xf, u16* __restrict__ Xfb,
    float* __restrict__ outL_plane)
{
  const int p = t >> 3;
  const int j0 = (t << 1) & 15;
  {
    float a0 = 0.f, a1 = 0.f;
    for (int k = 0; k < 16; ++k) {
      const float uk = m.U[p][k];
      a0 += uk * m.S[k][j0];
      a1 += uk * m.S[k][j0 + 1];
    }
    m.P[p][j0] = a0; m.P[p][j0 + 1] = a1;
  }
  __syncthreads();
  {
    const int q0 = (t & 7) << 3;
    float res[8];
#pragma unroll
    for (int e = 0; e < 8; ++e) res[e] = 0.f;
    for (int i = 0; i < 16; ++i) {
      const float pi = m.P[p][i];
#pragma unroll
      for (int e = 0; e < 8; ++e) res[e] += pi * m.V[q0 + e][i];
    }
    const size_t ko = ((size_t)b << 12) + (p << 6) + q0;
    float4* xo = reinterpret_cast<float4*>(Xf + ko);
    const float4 r0 = make_float4(res[0], res[1], res[2], res[3]);
    const float4 r1 = make_float4(res[4], res[5], res[6], res[7]);
    xo[0] = r0; xo[1] = r1;
    uint4 pk;
    pk.x = pack2bf(res[0], res[1]); pk.y = pack2bf(res[2], res[3]);
    pk.z = pack2bf(res[4], res[5]); pk.w = pack2bf(res[6], res[7]);
    *reinterpret_cast<uint4*>(Xfb + ko) = pk;
    if (outL_plane != nullptr) {
      float4* op = reinterpret_cast<float4*>(outL_plane + ko);
      op[0] = r0; op[1] = r1;
    }
  }
}

__global__ __launch_bounds__(512) void update_kernel(
    const u16* __restrict__ part, const float* __restrict__ bias,
    float* __restrict__ u_g, float* __restrict__ v_g, float* __restrict__ s_g,
    float* __restrict__ Xf, u16* __restrict__ Xfb,
    float* __restrict__ outL, int layer)
{
  const int b = blockIdx.x, t = threadIdx.x;
  __shared__ __align__(16) UpdSmem m;
  float* outL_plane = outL + (size_t)layer * PLANE;

  const size_t ub = (size_t)b << 10;
  {
    const float2 u2 = *reinterpret_cast<const float2*>(u_g + ub + (t << 1));
    const float2 v2 = *reinterpret_cast<const float2*>(v_g + ub + (t << 1));
    const int r = t >> 3, c = (t & 7) << 1;
    m.U[r][c] = u2.x; m.U[r][c + 1] = u2.y;
    m.V[r][c] = v2.x; m.V[r][c + 1] = v2.y;
    if (t < 256) m.S[t >> 4][t & 15] = s_g[((size_t)b << 8) + t];
  }
  __syncthreads();
  if (t < 16) m.sinv[t] = 1.0f / m.S[t][t];
  {
    const u16* p0 = part + ((size_t)b << 12) + (t << 3);
    float x[8];
#pragma unroll
    for (int e = 0; e < 8; ++e) x[e] = 0.f;
#pragma unroll
    for (int kzi = 0; kzi < SPLIT_K; ++kzi) {
      const uint4 v = *reinterpret_cast<const uint4*>(p0 + (size_t)kzi * PSTRIDE);
      x[0] += bf2f((u16)(v.x & 0xffff)); x[1] += bf2f((u16)(v.x >> 16));
      x[2] += bf2f((u16)(v.y & 0xffff)); x[3] += bf2f((u16)(v.y >> 16));
      x[4] += bf2f((u16)(v.z & 0xffff)); x[5] += bf2f((u16)(v.z >> 16));
      x[6] += bf2f((u16)(v.w & 0xffff)); x[7] += bf2f((u16)(v.w >> 16));
    }
    if (bias != nullptr) {
      const float4 b0 = *reinterpret_cast<const float4*>(bias + (t << 3));
      const float4 b1 = *reinterpret_cast<const float4*>(bias + (t << 3) + 4);
      x[0] += b0.x; x[1] += b0.y; x[2] += b0.z; x[3] += b0.w;
      x[4] += b1.x; x[5] += b1.y; x[6] += b1.z; x[7] += b1.w;
    }
    const int r = t >> 3, c = (t & 7) << 3;
#pragma unroll
    for (int e = 0; e < 8; ++e) x[e] = fmaxf(x[e], 0.f);
    float4* d0 = reinterpret_cast<float4*>(&m.dY[r][c]);
    d0[0] = make_float4(x[0], x[1], x[2], x[3]);
    d0[1] = make_float4(x[4], x[5], x[6], x[7]);
#pragma unroll
    for (int e = 0; e < 8; ++e) m.dYT[c + e][r] = x[e];
  }
  __syncthreads();
  const int p = t >> 3;
  const int j0 = (t << 1) & 15;
  {
    float a0 = 0.f, a1 = 0.f;
    for (int q = 0; q < 64; ++q) {
      const float d = m.dY[p][q];
      a0 += d * m.V[q][j0];
      a1 += d * m.V[q][j0 + 1];
    }
    float b0 = 0.f, b1 = 0.f;
    for (int r = 0; r < 64; ++r) {
      const float d = m.dYT[p][r];
      b0 += d * m.U[r][j0];
      b1 += d * m.U[r][j0 + 1];
    }
    m.P[p][j0] = a0; m.P[p][j0 + 1] = a1;
    m.Q[p][j0] = b0; m.Q[p][j0 + 1] = b1;
  }
  __syncthreads();
  {
    const int half = t & 1, i = t >> 5, j = (t >> 1) & 15;
    float a = 0.f;
    const int r0 = half << 5;
    for (int r = r0; r < r0 + 32; ++r) a += m.U[r][i] * m.P[r][j];
    m.RS[t] = a;
  }
  __syncthreads();
  if (t < 256) m.dSs[t >> 4][t & 15] = m.RS[t << 1] + m.RS[(t << 1) + 1];
  __syncthreads();
  for (int i = t; i < 1024; i += 512) {
    const int r = i >> 4, c = i & 15;
    const float sc = m.sinv[c];
    m.P[r][c] *= sc;
    m.Q[r][c] *= sc;
  }
  __syncthreads();

  stiefel_update512(m, m.U, m.P, t, u_g, ub);
  stiefel_update512(m, m.V, m.Q, t, v_g, ub);

  if (t < 256) {
    const int i = t >> 4, j = t & 15;
    const float ns = m.S[i][j] + 1e-3f * m.dSs[i][j];
    m.S[i][j] = ns;
    s_g[((size_t)b << 8) + t] = ns;
  }
  __syncthreads();
  write_xf_tail(m, t, b, Xf, Xfb, outL_plane);
}

// ---------------------------------------------------------------------------
// Init: unpack u, s, v from X (per-sample stride 3*1024); Xf0 = u s v^T.
// ---------------------------------------------------------------------------
__global__ __launch_bounds__(512) void init_kernel(
    const float* __restrict__ X, float* __restrict__ u_g, float* __restrict__ v_g,
    float* __restrict__ s_g, float* __restrict__ Xf, u16* __restrict__ Xfb)
{
  const int b = blockIdx.x, t = threadIdx.x;
  __shared__ __align__(16) UpdSmem m;
  const float* xb = X + (size_t)b * 3072;
  const size_t ub = (size_t)b << 10;
  {
    const float2 u2 = *reinterpret_cast<const float2*>(xb + (t << 1));
    const int r = t >> 3, c = (t & 7) << 1;
    m.U[r][c] = u2.x; m.U[r][c + 1] = u2.y;
    *reinterpret_cast<float2*>(u_g + ub + (t << 1)) = u2;
    if (t < 256) {
      const float sv = xb[1024 + t];
      m.S[t >> 4][t & 15] = sv;
      s_g[((size_t)b << 8) + t] = sv;
    }
    const float2 v2 = *reinterpret_cast<const float2*>(xb + 2048 + (t << 1));
    const int g2 = t << 1;
    const int iv = g2 >> 6, q = g2 & 63;
    m.V[q][iv] = v2.x; m.V[q + 1][iv] = v2.y;
    v_g[ub + (size_t)q * 16 + iv] = v2.x;
    v_g[ub + (size_t)(q + 1) * 16 + iv] = v2.y;
  }
  __syncthreads();
  write_xf_tail(m, t, b, Xf, Xfb, nullptr);
}

// ---------------------------------------------------------------------------
// Pack: outT[b,k,9] <- outL[9][b,k] via LDS, coalesced both sides.
// ---------------------------------------------------------------------------
__global__ __launch_bounds__(256) void pack_kernel(
    const float* __restrict__ outL, float* __restrict__ outT)
{
  const int t = threadIdx.x;
  const int base = blockIdx.x << 8;
  __shared__ float buf[256 * 9];
#pragma unroll
  for (int l = 0; l < 9; ++l)
    buf[t * 9 + l] = outL[(size_t)l * PLANE + base + t];
  __syncthreads();
  const float4* b4 = reinterpret_cast<const float4*>(buf);
  float4* o4 = reinterpret_cast<float4*>(outT + (size_t)base * 9);
  for (int i = t; i < 576; i += 256) o4[i] = b4[i];
}

// ---------------------------------------------------------------------------
// Classifier: logits = Xf @ Wc^T + bc ; softmax.
// ---------------------------------------------------------------------------
__global__ __launch_bounds__(256) void classifier_kernel(
    const float* __restrict__ Xf, const float* __restrict__ Wc,
    const float* __restrict__ bc, float* __restrict__ pred, float* __restrict__ cls)
{
  const int b = blockIdx.x, t = threadIdx.x;
  const int lane = t & 63, w = t >> 6;
  __shared__ float red[4][10];
  float acc[10];
#pragma unroll
  for (int c = 0; c < 10; ++c) acc[c] = 0.f;
  const float* xr = Xf + ((size_t)b << 12);
  for (int k = t; k < 4096; k += 256) {
    const float x = xr[k];
#pragma unroll
    for (int c = 0; c < 10; ++c) acc[c] += x * Wc[c * 4096 + k];
  }
#pragma unroll
  for (int c = 0; c < 10; ++c)
    for (int off = 32; off; off >>= 1) acc[c] += __shfl_xor(acc[c], off);
  if (lane == 0)
#pragma unroll
    for (int c = 0; c < 10; ++c) red[w][c] = acc[c];
  __syncthreads();
  if (t == 0) {
    float lg[10], ex[10];
    float m = -1e30f;
#pragma unroll
    for (int c = 0; c < 10; ++c) {
      lg[c] = red[0][c] + red[1][c] + red[2][c] + red[3][c] + bc[c];
      m = fmaxf(m, lg[c]);
    }
    float s = 0.f;
#pragma unroll
    for (int c = 0; c < 10; ++c) { ex[c] = expf(lg[c] - m); s += ex[c]; }
    const float inv = 1.f / s;
#pragma unroll
    for (int c = 0; c < 10; ++c) {
      cls[b * 10 + c] = lg[c];
      pred[b * 10 + c] = ex[c] * inv;
    }
  }
}

extern "C" void kernel_launch(void* const* d_in, const int* in_sizes, int n_in,
                              void* d_out, int out_size, void* d_ws, size_t ws_size,
                              hipStream_t stream) {
  (void)in_sizes; (void)n_in; (void)out_size; (void)ws_size;
  const float* X  = (const float*)d_in[0];
  const float* W0 = (const float*)d_in[1];
  const float* W  = (const float*)d_in[2];
  const float* bb = (const float*)d_in[3];
  const float* Wc = (const float*)d_in[4];
  const float* bc = (const float*)d_in[5];

  float* out_pred  = (float*)d_out;
  float* out_cls   = out_pred + 2560;
  float* out_trans = out_pred + 5120;

  char* ws = (char*)d_ws;
  float* Xf   = (float*)(ws);                      // 4 MB
  u16*   part = (u16*)  (ws + (4ull << 20));       // 8 MB (4 bf16 split-K planes)
  float* u_g  = (float*)(ws + (36ull << 20));      // 1 MB
  float* v_g  = (float*)(ws + (37ull << 20));      // 1 MB
  float* s_g  = (float*)(ws + (38ull << 20));      // 256 KB
  u16*   Xfb  = (u16*)  (ws + (39ull << 20));      // 2 MB
  float* outL = (float*)(ws + (41ull << 20));      // 36 MB (9 layer planes)

  init_kernel<<<NB, 512, 0, stream>>>(X, u_g, v_g, s_g, Xf, Xfb);
  for (int i = 0; i <= 8; ++i) {
    const float* Wl = (i == 0) ? W0 : W + (size_t)(i - 1) * DD * DD;
    // DIAGNOSTIC (this round only): gemm_kernel is idempotent — launch it
    // twice per layer. dur_us delta vs the 439-us baseline = 9*(G+overhead),
    // giving the first ground-truth per-kernel attribution of the session.
    gemm_kernel<<<dim3(64, 2 * SPLIT_K), 512, 0, stream>>>(Xfb, Wl, part);
    gemm_kernel<<<dim3(64, 2 * SPLIT_K), 512, 0, stream>>>(Xfb, Wl, part);
    update_kernel<<<NB, 512, 0, stream>>>(
        part, (i == 0) ? nullptr : (bb + (size_t)(i - 1) * DD),
        u_g, v_g, s_g, Xf, Xfb, outL, i);
  }
  pack_kernel<<<4096, 256, 0, stream>>>(outL, out_trans);
  classifier_kernel<<<NB, 256, 0, stream>>>(Xf, Wc, bc, out_pred, out_cls);
}

// Round 16
// 420.054 us; speedup vs baseline: 1.4525x; 1.4525x over previous
//
#include <hip/hip_runtime.h>
#include <math.h>

typedef unsigned short u16;
typedef unsigned int u32;
using bf16x8 = __attribute__((ext_vector_type(8))) short;
using f32x4  = __attribute__((ext_vector_type(4))) float;

#define DD 4096
#define NB 256            // batch
#define SPLIT_K 4
#define PSTRIDE (NB * DD) // elements per partial plane
#define PLANE (NB * DD)   // floats per transform layer plane

__device__ __forceinline__ u16 f2bf(float f) {
  unsigned int u = __float_as_uint(f);
  u += 0x7fffu + ((u >> 16) & 1u);   // RNE
  return (u16)(u >> 16);
}
__device__ __forceinline__ float bf2f(u16 h) {
  return __uint_as_float((u32)h << 16);
}
__device__ __forceinline__ unsigned int pack2bf(float a, float b) {
  return (unsigned int)f2bf(a) | ((unsigned int)f2bf(b) << 16);
}
__device__ __forceinline__ void async_cp16(const u16* g, u16* l) {
  __builtin_amdgcn_global_load_lds(
      (const __attribute__((address_space(1))) unsigned int*)g,
      (__attribute__((address_space(3))) unsigned int*)l, 16, 0, 0);
}

// ---------------------------------------------------------------------------
// GEMM (R11 body, unchanged): part[kz] = Xf(bf16) @ W^T, output bf16.
// Tile 128x64 (M-split 2), K-chunk 1024 (16 iters of BK=64). ~19us/layer
// incl. overhead (measured R15) — near the 64MB W-stream floor; left alone.
// ---------------------------------------------------------------------------
__global__ __launch_bounds__(512, 8) void gemm_kernel(
    const u16* __restrict__ A, const float* __restrict__ W,
    u16* __restrict__ part)
{
  const int nt = blockIdx.x;
  const int mt = blockIdx.y & 1;
  const int kz = blockIdx.y >> 1;
  const int t = threadIdx.x;
  const int w = t >> 6, l = t & 63;

  __shared__ __align__(16) u16 As[128 * 64];   // 16 KB
  __shared__ __align__(16) u16 Bs[64 * 64];    // 8 KB

  const int colg0 = nt << 6;
  const int m0 = mt << 7;
  const int k0 = kz << 10;                     // K-chunk of 1024

  f32x4 acc[2][2];
#pragma unroll
  for (int mi = 0; mi < 2; ++mi)
#pragma unroll
    for (int nj = 0; nj < 2; ++nj)
      acc[mi][nj] = (f32x4){0.f, 0.f, 0.f, 0.f};

  const int wm = w & 3, wn = w >> 2;
  const int lr = l & 15, lg = l >> 4;
  const int arow_l = (w << 3) + (l >> 3);
  const int acl = l & 7;
  const int bn_l = t >> 3;
  const int bcc = t & 7;

  for (int tt = 0; tt < 16; ++tt) {
    const int kk = k0 + (tt << 6);
    __syncthreads();
#pragma unroll
    for (int r2 = 0; r2 < 2; ++r2) {
      const int row = (r2 << 6) + arow_l;
      const int cs = acl ^ (row & 7);
      async_cp16(A + ((size_t)(m0 + row) << 12) + kk + (cs << 3),
                 &As[(r2 << 12) + (w << 9)]);
    }
    {
      const float* wsrc = W + ((size_t)(colg0 + bn_l) << 12) + kk + (bcc << 3);
      const float4 f0 = *reinterpret_cast<const float4*>(wsrc);
      const float4 f1 = *reinterpret_cast<const float4*>(wsrc + 4);
      uint4 pk;
      pk.x = pack2bf(f0.x, f0.y);
      pk.y = pack2bf(f0.z, f0.w);
      pk.z = pack2bf(f1.x, f1.y);
      pk.w = pack2bf(f1.z, f1.w);
      *reinterpret_cast<uint4*>(&Bs[(bn_l << 6) + ((bcc ^ (bn_l & 7)) << 3)]) = pk;
    }
    __syncthreads();
#pragma unroll
    for (int ks = 0; ks < 2; ++ks) {
      const int cg = (ks << 2) + lg;
      bf16x8 av[2], bv[2];
#pragma unroll
      for (int mi = 0; mi < 2; ++mi) {
        const int fr = (wm << 5) + (mi << 4) + lr;
        av[mi] = *reinterpret_cast<const bf16x8*>(&As[(fr << 6) + ((cg ^ (fr & 7)) << 3)]);
      }
#pragma unroll
      for (int nj = 0; nj < 2; ++nj) {
        const int fc = (wn << 5) + (nj << 4) + lr;
        bv[nj] = *reinterpret_cast<const bf16x8*>(&Bs[(fc << 6) + ((cg ^ (fc & 7)) << 3)]);
      }
#pragma unroll
      for (int mi = 0; mi < 2; ++mi)
#pragma unroll
        for (int nj = 0; nj < 2; ++nj)
          acc[mi][nj] = __builtin_amdgcn_mfma_f32_16x16x32_bf16(
              av[mi], bv[nj], acc[mi][nj], 0, 0, 0);
    }
  }

  u16* pout = part + (size_t)kz * PSTRIDE;
#pragma unroll
  for (int mi = 0; mi < 2; ++mi)
#pragma unroll
    for (int nj = 0; nj < 2; ++nj) {
      const int col = colg0 + (wn << 5) + (nj << 4) + lr;
#pragma unroll
      for (int j = 0; j < 4; ++j) {
        const int row = m0 + (wm << 5) + (mi << 4) + (lg << 2) + j;
        pout[((size_t)row << 12) + col] = f2bf(acc[mi][nj][j]);
      }
    }
}

// ---------------------------------------------------------------------------
// Update v2 — 9-barrier chain (was ~25). Key algebra:
//   R  = U^T P (unscaled)  ==  dS  (same reduction, computed once)
//   T1 = R*diag(sinv)  folded:  F[p][j] = sinv[j]*(P[p][j] - sum_k U[p][k]R[k][j])
//   U-side and V-side Stiefel updates run CONCURRENTLY (independent).
//   G2 = A^T A folded into the R phase (doesn't need F).
// ---------------------------------------------------------------------------
struct UpdSmem {
  float U[64][17], V[64][17], P[64][17], Q[64][17];   // 17.4 KB
  float S[16][16];
  float sinv[16];
  union {                                             // 35.1 KB
    struct {
      float dY[64][68];
      float dYT[64][69];
    };
    struct {
      float Fu[64][17], Fv[64][17];
      float R[16][17], Rv[16][17];
      float G1u[16][17], G1v[16][17];
      float G2u[16][17], G2v[16][17];
      float M1u[16][17], M1v[16][17];
    };
  };
};

// Phase 8+9 tail: P = U@S ; Xf = P@V^T (f32 + bf16 + optional layer plane)
__device__ __forceinline__ void write_xf_tail(
    UpdSmem& m, int t, int b, float* __restrict__ Xf, u16* __restrict__ Xfb,
    float* __restrict__ outL_plane)
{
  const int p = t >> 3;
  const int j0 = (t << 1) & 15;
  {
    float a0 = 0.f, a1 = 0.f;
    for (int k = 0; k < 16; ++k) {
      const float uk = m.U[p][k];
      a0 += uk * m.S[k][j0];
      a1 += uk * m.S[k][j0 + 1];
    }
    m.P[p][j0] = a0; m.P[p][j0 + 1] = a1;
  }
  __syncthreads();
  {
    const int q0 = (t & 7) << 3;
    float res[8];
#pragma unroll
    for (int e = 0; e < 8; ++e) res[e] = 0.f;
    for (int i = 0; i < 16; ++i) {
      const float pi = m.P[p][i];
#pragma unroll
      for (int e = 0; e < 8; ++e) res[e] += pi * m.V[q0 + e][i];
    }
    const size_t ko = ((size_t)b << 12) + (p << 6) + q0;
    float4* xo = reinterpret_cast<float4*>(Xf + ko);
    const float4 r0 = make_float4(res[0], res[1], res[2], res[3]);
    const float4 r1 = make_float4(res[4], res[5], res[6], res[7]);
    xo[0] = r0; xo[1] = r1;
    uint4 pk;
    pk.x = pack2bf(res[0], res[1]); pk.y = pack2bf(res[2], res[3]);
    pk.z = pack2bf(res[4], res[5]); pk.w = pack2bf(res[6], res[7]);
    *reinterpret_cast<uint4*>(Xfb + ko) = pk;
    if (outL_plane != nullptr) {
      float4* op = reinterpret_cast<float4*>(outL_plane + ko);
      op[0] = r0; op[1] = r1;
    }
  }
}

__global__ __launch_bounds__(512) void update_kernel(
    const u16* __restrict__ part, const float* __restrict__ bias,
    float* __restrict__ u_g, float* __restrict__ v_g, float* __restrict__ s_g,
    float* __restrict__ Xf, u16* __restrict__ Xfb,
    float* __restrict__ outL, int layer)
{
  const int b = blockIdx.x, t = threadIdx.x;
  __shared__ __align__(16) UpdSmem m;
  float* outL_plane = outL + (size_t)layer * PLANE;
  const size_t ub = (size_t)b << 10;
  const int p = t >> 3;              // 0..63
  const int j0 = (t << 1) & 15;      // even col

  // ---- Phase 1: all loads (U, V, S, sinv-from-global, dY+dYT) -- 1 barrier
  {
    const float2 u2 = *reinterpret_cast<const float2*>(u_g + ub + (t << 1));
    const float2 v2 = *reinterpret_cast<const float2*>(v_g + ub + (t << 1));
    const int r = t >> 3, c = (t & 7) << 1;
    m.U[r][c] = u2.x; m.U[r][c + 1] = u2.y;
    m.V[r][c] = v2.x; m.V[r][c + 1] = v2.y;
    if (t < 256) m.S[t >> 4][t & 15] = s_g[((size_t)b << 8) + t];
    if (t < 16)  m.sinv[t] = 1.0f / s_g[((size_t)b << 8) + t * 17];  // diag
    const u16* p0 = part + ((size_t)b << 12) + (t << 3);
    float x[8];
#pragma unroll
    for (int e = 0; e < 8; ++e) x[e] = 0.f;
#pragma unroll
    for (int kzi = 0; kzi < SPLIT_K; ++kzi) {
      const uint4 v = *reinterpret_cast<const uint4*>(p0 + (size_t)kzi * PSTRIDE);
      x[0] += bf2f((u16)(v.x & 0xffff)); x[1] += bf2f((u16)(v.x >> 16));
      x[2] += bf2f((u16)(v.y & 0xffff)); x[3] += bf2f((u16)(v.y >> 16));
      x[4] += bf2f((u16)(v.z & 0xffff)); x[5] += bf2f((u16)(v.z >> 16));
      x[6] += bf2f((u16)(v.w & 0xffff)); x[7] += bf2f((u16)(v.w >> 16));
    }
    if (bias != nullptr) {
      const float4 b0 = *reinterpret_cast<const float4*>(bias + (t << 3));
      const float4 b1 = *reinterpret_cast<const float4*>(bias + (t << 3) + 4);
      x[0] += b0.x; x[1] += b0.y; x[2] += b0.z; x[3] += b0.w;
      x[4] += b1.x; x[5] += b1.y; x[6] += b1.z; x[7] += b1.w;
    }
    const int r2 = t >> 3, c2 = (t & 7) << 3;
#pragma unroll
    for (int e = 0; e < 8; ++e) x[e] = fmaxf(x[e], 0.f);
    float4* d0 = reinterpret_cast<float4*>(&m.dY[r2][c2]);
    d0[0] = make_float4(x[0], x[1], x[2], x[3]);
    d0[1] = make_float4(x[4], x[5], x[6], x[7]);
#pragma unroll
    for (int e = 0; e < 8; ++e) m.dYT[c2 + e][r2] = x[e];
  }
  __syncthreads();

  // ---- Phase 2: P = dY@V, Q = dY^T@U (unscaled) -- 1 barrier
  {
    float a0 = 0.f, a1 = 0.f;
    for (int q = 0; q < 64; ++q) {
      const float d = m.dY[p][q];
      a0 += d * m.V[q][j0];
      a1 += d * m.V[q][j0 + 1];
    }
    float b0 = 0.f, b1 = 0.f;
    for (int r = 0; r < 64; ++r) {
      const float d = m.dYT[p][r];
      b0 += d * m.U[r][j0];
      b1 += d * m.U[r][j0 + 1];
    }
    m.P[p][j0] = a0; m.P[p][j0 + 1] = a1;
    m.Q[p][j0] = b0; m.Q[p][j0 + 1] = b1;
  }
  __syncthreads();   // dY/dYT dead; union overlay live from here

  // ---- Phase 3: R=U^T P (=dS), G2u=U^T U | Rv=V^T Q, G2v=V^T V -- 1 barrier
  {
    const int i = (t >> 4) & 15, j = t & 15;
    if (t < 256) {
      float r0 = 0.f, g0 = 0.f;
      for (int r = 0; r < 64; ++r) {
        const float ui = m.U[r][i];
        r0 += ui * m.P[r][j];
        g0 += ui * m.U[r][j];
      }
      m.R[i][j] = r0; m.G2u[i][j] = g0;
    } else {
      float r0 = 0.f, g0 = 0.f;
      for (int r = 0; r < 64; ++r) {
        const float vi = m.V[r][i];
        r0 += vi * m.Q[r][j];
        g0 += vi * m.V[r][j];
      }
      m.Rv[i][j] = r0; m.G2v[i][j] = g0;
    }
  }
  __syncthreads();

  // ---- Phase 4: Fu = sinv.(P - U@R), Fv = sinv.(Q - V@Rv) -- 1 barrier
  {
    float f0 = m.P[p][j0], f1 = m.P[p][j0 + 1];
    float g0 = m.Q[p][j0], g1 = m.Q[p][j0 + 1];
    for (int k = 0; k < 16; ++k) {
      const float uk = m.U[p][k], vk = m.V[p][k];
      f0 -= uk * m.R[k][j0];
      f1 -= uk * m.R[k][j0 + 1];
      g0 -= vk * m.Rv[k][j0];
      g1 -= vk * m.Rv[k][j0 + 1];
    }
    const float s0 = m.sinv[j0], s1 = m.sinv[j0 + 1];
    m.Fu[p][j0] = f0 * s0; m.Fu[p][j0 + 1] = f1 * s1;
    m.Fv[p][j0] = g0 * s0; m.Fv[p][j0 + 1] = g1 * s1;
  }
  __syncthreads();

  // ---- Phase 5: G1u = U^T Fu | G1v = V^T Fv -- 1 barrier
  {
    const int i = (t >> 4) & 15, j = t & 15;
    if (t < 256) {
      float g = 0.f;
      for (int r = 0; r < 64; ++r) g += m.U[r][i] * m.Fu[r][j];
      m.G1u[i][j] = g;
    } else {
      float g = 0.f;
      for (int r = 0; r < 64; ++r) g += m.V[r][i] * m.Fv[r][j];
      m.G1v[i][j] = g;
    }
  }
  __syncthreads();

  // ---- Phase 6: M1u = G1u@G2u | M1v = G1v@G2v -- 1 barrier
  {
    const int i = (t >> 4) & 15, j = t & 15;
    if (t < 256) {
      float mm = 0.f;
      for (int k = 0; k < 16; ++k) mm += m.G1u[i][k] * m.G2u[k][j];
      m.M1u[i][j] = mm;
    } else {
      float mm = 0.f;
      for (int k = 0; k < 16; ++k) mm += m.G1v[i][k] * m.G2v[k][j];
      m.M1v[i][j] = mm;
    }
  }
  __syncthreads();

  // ---- Phase 7: Unew = U - H^2 Fu@M1u, Vnew likewise; Snew = S + H*R
  //      (stash in regs, hazard barrier, write LDS + global) -- 2 barriers
  {
    float du0 = 0.f, du1 = 0.f, dv0 = 0.f, dv1 = 0.f;
    for (int k = 0; k < 16; ++k) {
      const float fu = m.Fu[p][k], fv = m.Fv[p][k];
      du0 += fu * m.M1u[k][j0];
      du1 += fu * m.M1u[k][j0 + 1];
      dv0 += fv * m.M1v[k][j0];
      dv1 += fv * m.M1v[k][j0 + 1];
    }
    const float nu0 = m.U[p][j0]     - 1e-6f * du0;
    const float nu1 = m.U[p][j0 + 1] - 1e-6f * du1;
    const float nv0 = m.V[p][j0]     - 1e-6f * dv0;
    const float nv1 = m.V[p][j0 + 1] - 1e-6f * dv1;
    float ns = 0.f;
    if (t < 256) {
      const int i = t >> 4, j = t & 15;
      ns = m.S[i][j] + 1e-3f * m.R[i][j];
    }
    __syncthreads();                 // all reads of U,V,S,R complete
    m.U[p][j0] = nu0; m.U[p][j0 + 1] = nu1;
    m.V[p][j0] = nv0; m.V[p][j0 + 1] = nv1;
    *reinterpret_cast<float2*>(u_g + ub + (p << 4) + j0) = make_float2(nu0, nu1);
    *reinterpret_cast<float2*>(v_g + ub + (p << 4) + j0) = make_float2(nv0, nv1);
    if (t < 256) {
      const int i = t >> 4, j = t & 15;
      m.S[i][j] = ns;
      s_g[((size_t)b << 8) + t] = ns;
    }
  }
  __syncthreads();

  // ---- Phases 8+9: Xf = (U@S)@V^T, write f32/bf16/plane -- 1 barrier
  write_xf_tail(m, t, b, Xf, Xfb, outL_plane);
}

// ---------------------------------------------------------------------------
// Init: unpack u, s, v from X (per-sample stride 3*1024); Xf0 = u s v^T.
// ---------------------------------------------------------------------------
__global__ __launch_bounds__(512) void init_kernel(
    const float* __restrict__ X, float* __restrict__ u_g, float* __restrict__ v_g,
    float* __restrict__ s_g, float* __restrict__ Xf, u16* __restrict__ Xfb)
{
  const int b = blockIdx.x, t = threadIdx.x;
  __shared__ __align__(16) UpdSmem m;
  const float* xb = X + (size_t)b * 3072;
  const size_t ub = (size_t)b << 10;
  {
    const float2 u2 = *reinterpret_cast<const float2*>(xb + (t << 1));
    const int r = t >> 3, c = (t & 7) << 1;
    m.U[r][c] = u2.x; m.U[r][c + 1] = u2.y;
    *reinterpret_cast<float2*>(u_g + ub + (t << 1)) = u2;
    if (t < 256) {
      const float sv = xb[1024 + t];
      m.S[t >> 4][t & 15] = sv;
      s_g[((size_t)b << 8) + t] = sv;
    }
    const float2 v2 = *reinterpret_cast<const float2*>(xb + 2048 + (t << 1));
    const int g2 = t << 1;
    const int iv = g2 >> 6, q = g2 & 63;
    m.V[q][iv] = v2.x; m.V[q + 1][iv] = v2.y;
    v_g[ub + (size_t)q * 16 + iv] = v2.x;
    v_g[ub + (size_t)(q + 1) * 16 + iv] = v2.y;
  }
  __syncthreads();
  write_xf_tail(m, t, b, Xf, Xfb, nullptr);
}

// ---------------------------------------------------------------------------
// Pack: outT[b,k,9] <- outL[9][b,k] via LDS, coalesced both sides.
// ---------------------------------------------------------------------------
__global__ __launch_bounds__(256) void pack_kernel(
    const float* __restrict__ outL, float* __restrict__ outT)
{
  const int t = threadIdx.x;
  const int base = blockIdx.x << 8;
  __shared__ float buf[256 * 9];
#pragma unroll
  for (int l = 0; l < 9; ++l)
    buf[t * 9 + l] = outL[(size_t)l * PLANE + base + t];
  __syncthreads();
  const float4* b4 = reinterpret_cast<const float4*>(buf);
  float4* o4 = reinterpret_cast<float4*>(outT + (size_t)base * 9);
  for (int i = t; i < 576; i += 256) o4[i] = b4[i];
}

// ---------------------------------------------------------------------------
// Classifier: logits = Xf @ Wc^T + bc ; softmax.
// ---------------------------------------------------------------------------
__global__ __launch_bounds__(256) void classifier_kernel(
    const float* __restrict__ Xf, const float* __restrict__ Wc,
    const float* __restrict__ bc, float* __restrict__ pred, float* __restrict__ cls)
{
  const int b = blockIdx.x, t = threadIdx.x;
  const int lane = t & 63, w = t >> 6;
  __shared__ float red[4][10];
  float acc[10];
#pragma unroll
  for (int c = 0; c < 10; ++c) acc[c] = 0.f;
  const float* xr = Xf + ((size_t)b << 12);
  for (int k = t; k < 4096; k += 256) {
    const float x = xr[k];
#pragma unroll
    for (int c = 0; c < 10; ++c) acc[c] += x * Wc[c * 4096 + k];
  }
#pragma unroll
  for (int c = 0; c < 10; ++c)
    for (int off = 32; off; off >>= 1) acc[c] += __shfl_xor(acc[c], off);
  if (lane == 0)
#pragma unroll
    for (int c = 0; c < 10; ++c) red[w][c] = acc[c];
  __syncthreads();
  if (t == 0) {
    float lg[10], ex[10];
    float m = -1e30f;
#pragma unroll
    for (int c = 0; c < 10; ++c) {
      lg[c] = red[0][c] + red[1][c] + red[2][c] + red[3][c] + bc[c];
      m = fmaxf(m, lg[c]);
    }
    float s = 0.f;
#pragma unroll
    for (int c = 0; c < 10; ++c) { ex[c] = expf(lg[c] - m); s += ex[c]; }
    const float inv = 1.f / s;
#pragma unroll
    for (int c = 0; c < 10; ++c) {
      cls[b * 10 + c] = lg[c];
      pred[b * 10 + c] = ex[c] * inv;
    }
  }
}

extern "C" void kernel_launch(void* const* d_in, const int* in_sizes, int n_in,
                              void* d_out, int out_size, void* d_ws, size_t ws_size,
                              hipStream_t stream) {
  (void)in_sizes; (void)n_in; (void)out_size; (void)ws_size;
  const float* X  = (const float*)d_in[0];
  const float* W0 = (const float*)d_in[1];
  const float* W  = (const float*)d_in[2];
  const float* bb = (const float*)d_in[3];
  const float* Wc = (const float*)d_in[4];
  const float* bc = (const float*)d_in[5];

  float* out_pred  = (float*)d_out;
  float* out_cls   = out_pred + 2560;
  float* out_trans = out_pred + 5120;

  char* ws = (char*)d_ws;
  float* Xf   = (float*)(ws);                      // 4 MB
  u16*   part = (u16*)  (ws + (4ull << 20));       // 8 MB (4 bf16 split-K planes)
  float* u_g  = (float*)(ws + (36ull << 20));      // 1 MB
  float* v_g  = (float*)(ws + (37ull << 20));      // 1 MB
  float* s_g  = (float*)(ws + (38ull << 20));      // 256 KB
  u16*   Xfb  = (u16*)  (ws + (39ull << 20));      // 2 MB
  float* outL = (float*)(ws + (41ull << 20));      // 36 MB (9 layer planes)

  init_kernel<<<NB, 512, 0, stream>>>(X, u_g, v_g, s_g, Xf, Xfb);
  for (int i = 0; i <= 8; ++i) {
    const float* Wl = (i == 0) ? W0 : W + (size_t)(i - 1) * DD * DD;
    gemm_kernel<<<dim3(64, 2 * SPLIT_K), 512, 0, stream>>>(Xfb, Wl, part);
    update_kernel<<<NB, 512, 0, stream>>>(
        part, (i == 0) ? nullptr : (bb + (size_t)(i - 1) * DD),
        u_g, v_g, s_g, Xf, Xfb, outL, i);
  }
  pack_kernel<<<4096, 256, 0, stream>>>(outL, out_trans);
  classifier_kernel<<<NB, 256, 0, stream>>>(Xf, Wc, bc, out_pred, out_cls);
}

// Round 17
// 402.333 us; speedup vs baseline: 1.5164x; 1.0440x over previous
//
#include <hip/hip_runtime.h>
#include <math.h>

typedef unsigned short u16;
typedef unsigned int u32;
using bf16x8 = __attribute__((ext_vector_type(8))) short;
using f32x4  = __attribute__((ext_vector_type(4))) float;

#define DD 4096
#define NB 256            // batch
#define SPLIT_K 4
#define PSTRIDE (NB * DD) // elements per partial plane
#define PLANE (NB * DD)   // floats per transform layer plane

__device__ __forceinline__ u16 f2bf(float f) {
  unsigned int u = __float_as_uint(f);
  u += 0x7fffu + ((u >> 16) & 1u);   // RNE
  return (u16)(u >> 16);
}
__device__ __forceinline__ float bf2f(u16 h) {
  return __uint_as_float((u32)h << 16);
}
__device__ __forceinline__ unsigned int pack2bf(float a, float b) {
  return (unsigned int)f2bf(a) | ((unsigned int)f2bf(b) << 16);
}
__device__ __forceinline__ void async_cp16(const u16* g, u16* l) {
  __builtin_amdgcn_global_load_lds(
      (const __attribute__((address_space(1))) unsigned int*)g,
      (__attribute__((address_space(3))) unsigned int*)l, 16, 0, 0);
}
// dot of 8 bf16 pairs packed in uint4 (lo/hi of each dword), f32 accumulate
__device__ __forceinline__ float dot8bf(const uint4 a, const uint4 b) {
  float s;
  s  = __uint_as_float(a.x << 16) * __uint_as_float(b.x << 16);
  s += __uint_as_float(a.x & 0xffff0000u) * __uint_as_float(b.x & 0xffff0000u);
  s += __uint_as_float(a.y << 16) * __uint_as_float(b.y << 16);
  s += __uint_as_float(a.y & 0xffff0000u) * __uint_as_float(b.y & 0xffff0000u);
  s += __uint_as_float(a.z << 16) * __uint_as_float(b.z << 16);
  s += __uint_as_float(a.z & 0xffff0000u) * __uint_as_float(b.z & 0xffff0000u);
  s += __uint_as_float(a.w << 16) * __uint_as_float(b.w << 16);
  s += __uint_as_float(a.w & 0xffff0000u) * __uint_as_float(b.w & 0xffff0000u);
  return s;
}
__device__ __forceinline__ float dot4f(const float4 a, const float4 b) {
  return a.x * b.x + a.y * b.y + a.z * b.z + a.w * b.w;
}

// ---------------------------------------------------------------------------
// GEMM (R11 body, unchanged): part[kz] = Xf(bf16) @ W^T, output bf16.
// ---------------------------------------------------------------------------
__global__ __launch_bounds__(512, 8) void gemm_kernel(
    const u16* __restrict__ A, const float* __restrict__ W,
    u16* __restrict__ part)
{
  const int nt = blockIdx.x;
  const int mt = blockIdx.y & 1;
  const int kz = blockIdx.y >> 1;
  const int t = threadIdx.x;
  const int w = t >> 6, l = t & 63;

  __shared__ __align__(16) u16 As[128 * 64];
  __shared__ __align__(16) u16 Bs[64 * 64];

  const int colg0 = nt << 6;
  const int m0 = mt << 7;
  const int k0 = kz << 10;

  f32x4 acc[2][2];
#pragma unroll
  for (int mi = 0; mi < 2; ++mi)
#pragma unroll
    for (int nj = 0; nj < 2; ++nj)
      acc[mi][nj] = (f32x4){0.f, 0.f, 0.f, 0.f};

  const int wm = w & 3, wn = w >> 2;
  const int lr = l & 15, lg = l >> 4;
  const int arow_l = (w << 3) + (l >> 3);
  const int acl = l & 7;
  const int bn_l = t >> 3;
  const int bcc = t & 7;

  for (int tt = 0; tt < 16; ++tt) {
    const int kk = k0 + (tt << 6);
    __syncthreads();
#pragma unroll
    for (int r2 = 0; r2 < 2; ++r2) {
      const int row = (r2 << 6) + arow_l;
      const int cs = acl ^ (row & 7);
      async_cp16(A + ((size_t)(m0 + row) << 12) + kk + (cs << 3),
                 &As[(r2 << 12) + (w << 9)]);
    }
    {
      const float* wsrc = W + ((size_t)(colg0 + bn_l) << 12) + kk + (bcc << 3);
      const float4 f0 = *reinterpret_cast<const float4*>(wsrc);
      const float4 f1 = *reinterpret_cast<const float4*>(wsrc + 4);
      uint4 pk;
      pk.x = pack2bf(f0.x, f0.y);
      pk.y = pack2bf(f0.z, f0.w);
      pk.z = pack2bf(f1.x, f1.y);
      pk.w = pack2bf(f1.z, f1.w);
      *reinterpret_cast<uint4*>(&Bs[(bn_l << 6) + ((bcc ^ (bn_l & 7)) << 3)]) = pk;
    }
    __syncthreads();
#pragma unroll
    for (int ks = 0; ks < 2; ++ks) {
      const int cg = (ks << 2) + lg;
      bf16x8 av[2], bv[2];
#pragma unroll
      for (int mi = 0; mi < 2; ++mi) {
        const int fr = (wm << 5) + (mi << 4) + lr;
        av[mi] = *reinterpret_cast<const bf16x8*>(&As[(fr << 6) + ((cg ^ (fr & 7)) << 3)]);
      }
#pragma unroll
      for (int nj = 0; nj < 2; ++nj) {
        const int fc = (wn << 5) + (nj << 4) + lr;
        bv[nj] = *reinterpret_cast<const bf16x8*>(&Bs[(fc << 6) + ((cg ^ (fc & 7)) << 3)]);
      }
#pragma unroll
      for (int mi = 0; mi < 2; ++mi)
#pragma unroll
        for (int nj = 0; nj < 2; ++nj)
          acc[mi][nj] = __builtin_amdgcn_mfma_f32_16x16x32_bf16(
              av[mi], bv[nj], acc[mi][nj], 0, 0, 0);
    }
  }

  u16* pout = part + (size_t)kz * PSTRIDE;
#pragma unroll
  for (int mi = 0; mi < 2; ++mi)
#pragma unroll
    for (int nj = 0; nj < 2; ++nj) {
      const int col = colg0 + (wn << 5) + (nj << 4) + lr;
#pragma unroll
      for (int j = 0; j < 4; ++j) {
        const int row = m0 + (wm << 5) + (mi << 4) + (lg << 2) + j;
        pout[((size_t)row << 12) + col] = f2bf(acc[mi][nj][j]);
      }
    }
}

// ---------------------------------------------------------------------------
// Update v3 — bf16-LDS + b128 reads. All bf16-ized values sit on H/H^2-scaled
// paths; f32 kept for state (U,V,S), F/du, and the Xf tail.
// ---------------------------------------------------------------------------
struct UpdSmem {
  float U[64][20], V[64][20], P[64][20];          // f32 state, b128-aligned rows
  u16 UTb[16][72], VTb[16][72], PTb[16][72], QTb[16][72];  // bf16 transposes
  float S[16][16], ST[16][16];
  float sinv[16];
  union {
    struct {                                      // live ph1..ph2
      u16 dYb[64][72];                            // row-major bf16
      u16 dYTb[64][80];                           // transpose, chunk-swizzled
    };
    struct {                                      // live ph3..ph7
      float Fu[64][20], Fv[64][20];
      u16 FuTb[16][72], FvTb[16][72];
      float R[16][20], RT[16][20], RvT[16][20];
      float G1u[16][20], G1v[16][20];
      float G2u[16][20], G2v[16][20];
      float M1uT[16][20], M1vT[16][20];
    };
  };
};

// tail: P = U@S (via ST); Xf = P@V^T  (f32, 2 barriers)
__device__ __forceinline__ void write_xf_tail(
    UpdSmem& m, int t, int b, float* __restrict__ Xf, u16* __restrict__ Xfb,
    float* __restrict__ outL_plane)
{
  const int p = t >> 3;
  const int j0 = (t << 1) & 15;
  {
    const float4* u4 = reinterpret_cast<const float4*>(&m.U[p][0]);
    const float4* sa = reinterpret_cast<const float4*>(&m.ST[j0][0]);
    const float4* sb = reinterpret_cast<const float4*>(&m.ST[j0 + 1][0]);
    float a0 = 0.f, a1 = 0.f;
#pragma unroll
    for (int k4 = 0; k4 < 4; ++k4) {
      const float4 uu = u4[k4];
      a0 += dot4f(uu, sa[k4]);
      a1 += dot4f(uu, sb[k4]);
    }
    m.P[p][j0] = a0; m.P[p][j0 + 1] = a1;
  }
  __syncthreads();
  {
    const int q0 = (t & 7) << 3;
    float4 pr[4];
    const float4* p4 = reinterpret_cast<const float4*>(&m.P[p][0]);
#pragma unroll
    for (int k4 = 0; k4 < 4; ++k4) pr[k4] = p4[k4];
    float res[8];
#pragma unroll
    for (int e = 0; e < 8; ++e) {
      const float4* v4 = reinterpret_cast<const float4*>(&m.V[q0 + e][0]);
      res[e] = dot4f(pr[0], v4[0]) + dot4f(pr[1], v4[1]) +
               dot4f(pr[2], v4[2]) + dot4f(pr[3], v4[3]);
    }
    const size_t ko = ((size_t)b << 12) + (p << 6) + q0;
    float4* xo = reinterpret_cast<float4*>(Xf + ko);
    const float4 r0 = make_float4(res[0], res[1], res[2], res[3]);
    const float4 r1 = make_float4(res[4], res[5], res[6], res[7]);
    xo[0] = r0; xo[1] = r1;
    uint4 pk;
    pk.x = pack2bf(res[0], res[1]); pk.y = pack2bf(res[2], res[3]);
    pk.z = pack2bf(res[4], res[5]); pk.w = pack2bf(res[6], res[7]);
    *reinterpret_cast<uint4*>(Xfb + ko) = pk;
    if (outL_plane != nullptr) {
      float4* op = reinterpret_cast<float4*>(outL_plane + ko);
      op[0] = r0; op[1] = r1;
    }
  }
}

__global__ __launch_bounds__(512) void update_kernel(
    const u16* __restrict__ part, const float* __restrict__ bias,
    float* __restrict__ u_g, float* __restrict__ v_g, float* __restrict__ s_g,
    float* __restrict__ Xf, u16* __restrict__ Xfb,
    float* __restrict__ outL, int layer)
{
  const int b = blockIdx.x, t = threadIdx.x;
  __shared__ __align__(16) UpdSmem m;
  float* outL_plane = outL + (size_t)layer * PLANE;
  const size_t ub = (size_t)b << 10;
  const int p8 = t >> 3;             // 0..63
  const int j0 = (t << 1) & 15;      // even col

  // ---- Phase 1: loads + bf16 copies ----------------------------------------
  {
    const float2 u2 = *reinterpret_cast<const float2*>(u_g + ub + (t << 1));
    const float2 v2 = *reinterpret_cast<const float2*>(v_g + ub + (t << 1));
    const int r = t >> 3, c = (t & 7) << 1;
    m.U[r][c] = u2.x; m.U[r][c + 1] = u2.y;
    m.V[r][c] = v2.x; m.V[r][c + 1] = v2.y;
    m.UTb[c][r] = f2bf(u2.x); m.UTb[c + 1][r] = f2bf(u2.y);
    m.VTb[c][r] = f2bf(v2.x); m.VTb[c + 1][r] = f2bf(v2.y);
    if (t < 256) {
      const float sv = s_g[((size_t)b << 8) + t];
      m.S[t >> 4][t & 15] = sv;
      m.ST[t & 15][t >> 4] = sv;
    }
    if (t < 16) m.sinv[t] = 1.0f / s_g[((size_t)b << 8) + t * 17];
    const u16* p0 = part + ((size_t)b << 12) + (t << 3);
    float x[8];
#pragma unroll
    for (int e = 0; e < 8; ++e) x[e] = 0.f;
#pragma unroll
    for (int kzi = 0; kzi < SPLIT_K; ++kzi) {
      const uint4 v = *reinterpret_cast<const uint4*>(p0 + (size_t)kzi * PSTRIDE);
      x[0] += bf2f((u16)(v.x & 0xffff)); x[1] += bf2f((u16)(v.x >> 16));
      x[2] += bf2f((u16)(v.y & 0xffff)); x[3] += bf2f((u16)(v.y >> 16));
      x[4] += bf2f((u16)(v.z & 0xffff)); x[5] += bf2f((u16)(v.z >> 16));
      x[6] += bf2f((u16)(v.w & 0xffff)); x[7] += bf2f((u16)(v.w >> 16));
    }
    if (bias != nullptr) {
      const float4 b0 = *reinterpret_cast<const float4*>(bias + (t << 3));
      const float4 b1 = *reinterpret_cast<const float4*>(bias + (t << 3) + 4);
      x[0] += b0.x; x[1] += b0.y; x[2] += b0.z; x[3] += b0.w;
      x[4] += b1.x; x[5] += b1.y; x[6] += b1.z; x[7] += b1.w;
    }
#pragma unroll
    for (int e = 0; e < 8; ++e) x[e] = fmaxf(x[e], 0.f);
    const int r2 = t >> 3, c2 = (t & 7) << 3, sw = (t & 7) << 3;
    uint4 pk;
    pk.x = pack2bf(x[0], x[1]); pk.y = pack2bf(x[2], x[3]);
    pk.z = pack2bf(x[4], x[5]); pk.w = pack2bf(x[6], x[7]);
    *reinterpret_cast<uint4*>(&m.dYb[r2][c2]) = pk;
#pragma unroll
    for (int e = 0; e < 8; ++e) m.dYTb[c2 + e][r2 ^ sw] = f2bf(x[e]);
  }
  __syncthreads();

  // ---- Phase 2: P = dY@V (t<256), Q = dY^T@U (t>=256); 4 outputs/thread ----
  {
    const int tt = t & 255;
    const int p = tt & 63, jg = (tt >> 6) << 2;
    float a[4] = {0.f, 0.f, 0.f, 0.f};
    if (t < 256) {
      const uint4* dy = reinterpret_cast<const uint4*>(&m.dYb[p][0]);
#pragma unroll
      for (int r8 = 0; r8 < 8; ++r8) {
        const uint4 d = dy[r8];
#pragma unroll
        for (int e = 0; e < 4; ++e)
          a[e] += dot8bf(d, reinterpret_cast<const uint4*>(&m.VTb[jg + e][0])[r8]);
      }
#pragma unroll
      for (int e = 0; e < 4; ++e) m.PTb[jg + e][p] = f2bf(a[e]);
    } else {
      const int sw = (p >> 3) & 7;
      const uint4* dy = reinterpret_cast<const uint4*>(&m.dYTb[p][0]);
#pragma unroll
      for (int r8 = 0; r8 < 8; ++r8) {
        const uint4 d = dy[r8 ^ sw];
#pragma unroll
        for (int e = 0; e < 4; ++e)
          a[e] += dot8bf(d, reinterpret_cast<const uint4*>(&m.UTb[jg + e][0])[r8]);
      }
#pragma unroll
      for (int e = 0; e < 4; ++e) m.QTb[jg + e][p] = f2bf(a[e]);
    }
  }
  __syncthreads();   // dYb/dYTb dead; overlay live

  // ---- Phase 3: R=U^T P, G2u=U^T U | Rv=V^T Q, G2v=V^T V -------------------
  {
    const int tt = t & 255, i = tt >> 4, j = tt & 15;
    if (t < 256) {
      float r0 = 0.f, g0 = 0.f;
#pragma unroll
      for (int r8 = 0; r8 < 8; ++r8) {
        const uint4 ui = reinterpret_cast<const uint4*>(&m.UTb[i][0])[r8];
        r0 += dot8bf(ui, reinterpret_cast<const uint4*>(&m.PTb[j][0])[r8]);
        g0 += dot8bf(ui, reinterpret_cast<const uint4*>(&m.UTb[j][0])[r8]);
      }
      m.R[i][j] = r0; m.RT[j][i] = r0; m.G2u[i][j] = g0;
    } else {
      float r0 = 0.f, g0 = 0.f;
#pragma unroll
      for (int r8 = 0; r8 < 8; ++r8) {
        const uint4 vi = reinterpret_cast<const uint4*>(&m.VTb[i][0])[r8];
        r0 += dot8bf(vi, reinterpret_cast<const uint4*>(&m.QTb[j][0])[r8]);
        g0 += dot8bf(vi, reinterpret_cast<const uint4*>(&m.VTb[j][0])[r8]);
      }
      m.RvT[j][i] = r0; m.G2v[i][j] = g0;
    }
  }
  __syncthreads();

  // ---- Phase 4: Fu = sinv.(P - U@R), Fv = sinv.(Q - V@Rv) ------------------
  {
    float f0 = bf2f(m.PTb[j0][p8]), f1 = bf2f(m.PTb[j0 + 1][p8]);
    float g0 = bf2f(m.QTb[j0][p8]), g1 = bf2f(m.QTb[j0 + 1][p8]);
    const float4* u4 = reinterpret_cast<const float4*>(&m.U[p8][0]);
    const float4* v4 = reinterpret_cast<const float4*>(&m.V[p8][0]);
    const float4* ra = reinterpret_cast<const float4*>(&m.RT[j0][0]);
    const float4* rb = reinterpret_cast<const float4*>(&m.RT[j0 + 1][0]);
    const float4* rc = reinterpret_cast<const float4*>(&m.RvT[j0][0]);
    const float4* rd = reinterpret_cast<const float4*>(&m.RvT[j0 + 1][0]);
#pragma unroll
    for (int k4 = 0; k4 < 4; ++k4) {
      const float4 uu = u4[k4], vv = v4[k4];
      f0 -= dot4f(uu, ra[k4]);
      f1 -= dot4f(uu, rb[k4]);
      g0 -= dot4f(vv, rc[k4]);
      g1 -= dot4f(vv, rd[k4]);
    }
    const float s0 = m.sinv[j0], s1 = m.sinv[j0 + 1];
    f0 *= s0; f1 *= s1; g0 *= s0; g1 *= s1;
    *reinterpret_cast<float2*>(&m.Fu[p8][j0]) = make_float2(f0, f1);
    *reinterpret_cast<float2*>(&m.Fv[p8][j0]) = make_float2(g0, g1);
    m.FuTb[j0][p8] = f2bf(f0); m.FuTb[j0 + 1][p8] = f2bf(f1);
    m.FvTb[j0][p8] = f2bf(g0); m.FvTb[j0 + 1][p8] = f2bf(g1);
  }
  __syncthreads();

  // ---- Phase 5: G1u = U^T Fu | G1v = V^T Fv --------------------------------
  {
    const int tt = t & 255, i = tt >> 4, j = tt & 15;
    if (t < 256) {
      float g = 0.f;
#pragma unroll
      for (int r8 = 0; r8 < 8; ++r8)
        g += dot8bf(reinterpret_cast<const uint4*>(&m.UTb[i][0])[r8],
                    reinterpret_cast<const uint4*>(&m.FuTb[j][0])[r8]);
      m.G1u[i][j] = g;
    } else {
      float g = 0.f;
#pragma unroll
      for (int r8 = 0; r8 < 8; ++r8)
        g += dot8bf(reinterpret_cast<const uint4*>(&m.VTb[i][0])[r8],
                    reinterpret_cast<const uint4*>(&m.FvTb[j][0])[r8]);
      m.G1v[i][j] = g;
    }
  }
  __syncthreads();

  // ---- Phase 6: M1uT = (G1u@G2u)^T | M1vT ----------------------------------
  {
    const int tt = t & 255, i = tt >> 4, j = tt & 15;
    if (t < 256) {
      float mm = 0.f;
#pragma unroll
      for (int k4 = 0; k4 < 4; ++k4)
        mm += dot4f(reinterpret_cast<const float4*>(&m.G1u[i][0])[k4],
                    reinterpret_cast<const float4*>(&m.G2u[j][0])[k4]);  // G2 symmetric
      m.M1uT[j][i] = mm;
    } else {
      float mm = 0.f;
#pragma unroll
      for (int k4 = 0; k4 < 4; ++k4)
        mm += dot4f(reinterpret_cast<const float4*>(&m.G1v[i][0])[k4],
                    reinterpret_cast<const float4*>(&m.G2v[j][0])[k4]);
      m.M1vT[j][i] = mm;
    }
  }
  __syncthreads();

  // ---- Phase 7: state update -----------------------------------------------
  {
    float du0 = 0.f, du1 = 0.f, dv0 = 0.f, dv1 = 0.f;
    const float4* fu4 = reinterpret_cast<const float4*>(&m.Fu[p8][0]);
    const float4* fv4 = reinterpret_cast<const float4*>(&m.Fv[p8][0]);
    const float4* ma = reinterpret_cast<const float4*>(&m.M1uT[j0][0]);
    const float4* mb = reinterpret_cast<const float4*>(&m.M1uT[j0 + 1][0]);
    const float4* mc = reinterpret_cast<const float4*>(&m.M1vT[j0][0]);
    const float4* md = reinterpret_cast<const float4*>(&m.M1vT[j0 + 1][0]);
#pragma unroll
    for (int k4 = 0; k4 < 4; ++k4) {
      const float4 fu = fu4[k4], fv = fv4[k4];
      du0 += dot4f(fu, ma[k4]);
      du1 += dot4f(fu, mb[k4]);
      dv0 += dot4f(fv, mc[k4]);
      dv1 += dot4f(fv, md[k4]);
    }
    const float nu0 = m.U[p8][j0]     - 1e-6f * du0;
    const float nu1 = m.U[p8][j0 + 1] - 1e-6f * du1;
    const float nv0 = m.V[p8][j0]     - 1e-6f * dv0;
    const float nv1 = m.V[p8][j0 + 1] - 1e-6f * dv1;
    float ns = 0.f;
    if (t < 256) ns = m.S[t >> 4][t & 15] + 1e-3f * m.R[t >> 4][t & 15];
    __syncthreads();
    m.U[p8][j0] = nu0; m.U[p8][j0 + 1] = nu1;
    m.V[p8][j0] = nv0; m.V[p8][j0 + 1] = nv1;
    *reinterpret_cast<float2*>(u_g + ub + (p8 << 4) + j0) = make_float2(nu0, nu1);
    *reinterpret_cast<float2*>(v_g + ub + (p8 << 4) + j0) = make_float2(nv0, nv1);
    if (t < 256) {
      m.S[t >> 4][t & 15] = ns;
      m.ST[t & 15][t >> 4] = ns;
      s_g[((size_t)b << 8) + t] = ns;
    }
  }
  __syncthreads();

  // ---- Phases 8+9: Xf tail --------------------------------------------------
  write_xf_tail(m, t, b, Xf, Xfb, outL_plane);
}

// ---------------------------------------------------------------------------
// Init: unpack u, s, v; Xf0 = u s v^T.
// ---------------------------------------------------------------------------
__global__ __launch_bounds__(512) void init_kernel(
    const float* __restrict__ X, float* __restrict__ u_g, float* __restrict__ v_g,
    float* __restrict__ s_g, float* __restrict__ Xf, u16* __restrict__ Xfb)
{
  const int b = blockIdx.x, t = threadIdx.x;
  __shared__ __align__(16) UpdSmem m;
  const float* xb = X + (size_t)b * 3072;
  const size_t ub = (size_t)b << 10;
  {
    const float2 u2 = *reinterpret_cast<const float2*>(xb + (t << 1));
    const int r = t >> 3, c = (t & 7) << 1;
    m.U[r][c] = u2.x; m.U[r][c + 1] = u2.y;
    *reinterpret_cast<float2*>(u_g + ub + (t << 1)) = u2;
    if (t < 256) {
      const float sv = xb[1024 + t];
      m.S[t >> 4][t & 15] = sv;
      m.ST[t & 15][t >> 4] = sv;
      s_g[((size_t)b << 8) + t] = sv;
    }
    const float2 v2 = *reinterpret_cast<const float2*>(xb + 2048 + (t << 1));
    const int g2 = t << 1;
    const int iv = g2 >> 6, q = g2 & 63;
    m.V[q][iv] = v2.x; m.V[q + 1][iv] = v2.y;
    v_g[ub + (size_t)q * 16 + iv] = v2.x;
    v_g[ub + (size_t)(q + 1) * 16 + iv] = v2.y;
  }
  __syncthreads();
  write_xf_tail(m, t, b, Xf, Xfb, nullptr);
}

// ---------------------------------------------------------------------------
// Pack + classifier fused: outT[b,k,9] <- outL[9][b,k]; bid<256 also computes
// logits/softmax for sample bid.
// ---------------------------------------------------------------------------
__global__ __launch_bounds__(256) void pack_cls_kernel(
    const float* __restrict__ outL, float* __restrict__ outT,
    const float* __restrict__ Xf, const float* __restrict__ Wc,
    const float* __restrict__ bc, float* __restrict__ pred,
    float* __restrict__ cls)
{
  const int t = threadIdx.x;
  const int bid = blockIdx.x;
  __shared__ float buf[256 * 9];
  __shared__ float red[4][10];
  {
    const int base = bid << 8;
#pragma unroll
    for (int l = 0; l < 9; ++l)
      buf[t * 9 + l] = outL[(size_t)l * PLANE + base + t];
    __syncthreads();
    const float4* b4 = reinterpret_cast<const float4*>(buf);
    float4* o4 = reinterpret_cast<float4*>(outT + (size_t)base * 9);
    for (int i = t; i < 576; i += 256) o4[i] = b4[i];
  }
  if (bid >= NB) return;
  const int b = bid;
  const int lane = t & 63, w = t >> 6;
  float acc[10];
#pragma unroll
  for (int c = 0; c < 10; ++c) acc[c] = 0.f;
  const float* xr = Xf + ((size_t)b << 12);
  for (int k = t; k < 4096; k += 256) {
    const float x = xr[k];
#pragma unroll
    for (int c = 0; c < 10; ++c) acc[c] += x * Wc[c * 4096 + k];
  }
#pragma unroll
  for (int c = 0; c < 10; ++c)
    for (int off = 32; off; off >>= 1) acc[c] += __shfl_xor(acc[c], off);
  if (lane == 0)
#pragma unroll
    for (int c = 0; c < 10; ++c) red[w][c] = acc[c];
  __syncthreads();
  if (t == 0) {
    float lg[10], ex[10];
    float mx = -1e30f;
#pragma unroll
    for (int c = 0; c < 10; ++c) {
      lg[c] = red[0][c] + red[1][c] + red[2][c] + red[3][c] + bc[c];
      mx = fmaxf(mx, lg[c]);
    }
    float s = 0.f;
#pragma unroll
    for (int c = 0; c < 10; ++c) { ex[c] = expf(lg[c] - mx); s += ex[c]; }
    const float inv = 1.f / s;
#pragma unroll
    for (int c = 0; c < 10; ++c) {
      cls[b * 10 + c] = lg[c];
      pred[b * 10 + c] = ex[c] * inv;
    }
  }
}

extern "C" void kernel_launch(void* const* d_in, const int* in_sizes, int n_in,
                              void* d_out, int out_size, void* d_ws, size_t ws_size,
                              hipStream_t stream) {
  (void)in_sizes; (void)n_in; (void)out_size; (void)ws_size;
  const float* X  = (const float*)d_in[0];
  const float* W0 = (const float*)d_in[1];
  const float* W  = (const float*)d_in[2];
  const float* bb = (const float*)d_in[3];
  const float* Wc = (const float*)d_in[4];
  const float* bc = (const float*)d_in[5];

  float* out_pred  = (float*)d_out;
  float* out_cls   = out_pred + 2560;
  float* out_trans = out_pred + 5120;

  char* ws = (char*)d_ws;
  float* Xf   = (float*)(ws);                      // 4 MB
  u16*   part = (u16*)  (ws + (4ull << 20));       // 8 MB (4 bf16 split-K planes)
  float* u_g  = (float*)(ws + (36ull << 20));      // 1 MB
  float* v_g  = (float*)(ws + (37ull << 20));      // 1 MB
  float* s_g  = (float*)(ws + (38ull << 20));      // 256 KB
  u16*   Xfb  = (u16*)  (ws + (39ull << 20));      // 2 MB
  float* outL = (float*)(ws + (41ull << 20));      // 36 MB (9 layer planes)

  init_kernel<<<NB, 512, 0, stream>>>(X, u_g, v_g, s_g, Xf, Xfb);
  for (int i = 0; i <= 8; ++i) {
    const float* Wl = (i == 0) ? W0 : W + (size_t)(i - 1) * DD * DD;
    gemm_kernel<<<dim3(64, 2 * SPLIT_K), 512, 0, stream>>>(Xfb, Wl, part);
    update_kernel<<<NB, 512, 0, stream>>>(
        part, (i == 0) ? nullptr : (bb + (size_t)(i - 1) * DD),
        u_g, v_g, s_g, Xf, Xfb, outL, i);
  }
  pack_cls_kernel<<<4096, 256, 0, stream>>>(outL, out_trans, Xf, Wc, bc,
                                            out_pred, out_cls);
}